// Round 4
// baseline (52.593 us; speedup 1.0000x reference)
//
#include <hip/hip_runtime.h>

// Problem constants (B=4, C=4, H=64, W=64, K=8192)
static constexpr int TOKENS = 16384;   // B*H*W
static constexpr int HW     = 4096;    // H*W
static constexpr int NSLICE = 128;     // codebook slices
static constexpr int SLICE  = 64;      // entries per slice (NSLICE*SLICE == 8192)
static constexpr int NGROUP = 16;      // token groups
static constexpr int GTOK   = 1024;    // tokens per group (NGROUP*GTOK == TOKENS)
static constexpr int TPT    = 4;       // tokens per thread in dist kernel

// ---------------------------------------------------------------------------
// Kernel 1: fused pre-quant conv + sliced distance argmin.
// 2048 blocks = 128 slices x 16 groups -> 8 blocks/CU = 8 waves/SIMD.
// NO LDS: codebook slice is wave-uniform -> scalar (SMEM) loads on the
// s_load pipe; inner loop is pure VALU (4 fma + cmp + 2 sel per pair).
// ---------------------------------------------------------------------------
__global__ __launch_bounds__(256, 8) void k_dist(
    const float* __restrict__ z,      // [B,C,H,W]
    const float* __restrict__ w,      // [4,4]
    const float* __restrict__ bias,   // [4]
    const float4* __restrict__ CB,    // [8192]
    float2* __restrict__ P,           // [NSLICE*TOKENS] (min_val, idx bits)
    float* __restrict__ acc,
    unsigned* __restrict__ cnt)
{
    const int bx  = blockIdx.x;
    const int g   = bx & (NGROUP - 1);
    const int s   = bx >> 4;          // NGROUP == 16
    const int tid = threadIdx.x;
    if (bx == 0 && tid == 0) { *acc = 0.0f; *cnt = 0u; }

    // Per-thread tokens: 1x1 conv recomputed from z (w/bias uniform -> s_loads).
    const int tbase = g * GTOK + tid;
    float m0[TPT], m1[TPT], m2[TPT], m3[TPT], bv[TPT];
    int bi[TPT];
#pragma unroll
    for (int j = 0; j < TPT; ++j) {
        int t = tbase + j * 256;
        int b = t >> 12;
        int n = t & (HW - 1);
        const float* zb = z + b * (4 * HW) + n;
        float z0 = zb[0], z1 = zb[HW], z2 = zb[2 * HW], z3 = zb[3 * HW];
        float x0 = fmaf(w[3],  z3, fmaf(w[2],  z2, fmaf(w[1],  z1, fmaf(w[0],  z0, bias[0]))));
        float x1 = fmaf(w[7],  z3, fmaf(w[6],  z2, fmaf(w[5],  z1, fmaf(w[4],  z0, bias[1]))));
        float x2 = fmaf(w[11], z3, fmaf(w[10], z2, fmaf(w[9],  z1, fmaf(w[8],  z0, bias[2]))));
        float x3 = fmaf(w[15], z3, fmaf(w[14], z2, fmaf(w[13], z1, fmaf(w[12], z0, bias[3]))));
        m0[j] = -2.0f * x0;
        m1[j] = -2.0f * x1;
        m2[j] = -2.0f * x2;
        m3[j] = -2.0f * x3;
        bv[j] = 3.0e38f;
        bi[j] = 0;
    }

    // Wave-uniform slice base -> scalar loads (s_load_dwordx4) for the codebook.
    const int sbase = __builtin_amdgcn_readfirstlane(s * SLICE);
    const float4* __restrict__ cs = CB + sbase;

    // score = |c|^2 - 2 x.c  (per-token |x|^2 is argmin-invariant)
#pragma unroll 8
    for (int e = 0; e < SLICE; ++e) {
        float4 c = cs[e];             // uniform address -> SMEM pipe
        float cn = fmaf(c.w, c.w, fmaf(c.z, c.z, fmaf(c.y, c.y, c.x * c.x)));
#pragma unroll
        for (int j = 0; j < TPT; ++j) {
            float d = fmaf(m0[j], c.x, fmaf(m1[j], c.y, fmaf(m2[j], c.z, fmaf(m3[j], c.w, cn))));
            bool lt = d < bv[j];      // strict < keeps lowest idx
            bv[j] = lt ? d : bv[j];
            bi[j] = lt ? e : bi[j];   // e <= 63: inline-const/SGPR cndmask
        }
    }

#pragma unroll
    for (int j = 0; j < TPT; ++j) {
        int t = tbase + j * 256;
        P[s * TOKENS + t] = make_float2(bv[j], __int_as_float(sbase + bi[j]));
    }
}

// ---------------------------------------------------------------------------
// Kernel 2: reduce 128 slice-partials (4 threads/token) + gather + output +
// loss, fused finalize via block counter. 256 blocks x 256 threads.
// ---------------------------------------------------------------------------
__global__ __launch_bounds__(256) void k_out(
    const float* __restrict__ z,
    const float* __restrict__ w,
    const float* __restrict__ bias,
    const float4* __restrict__ CB,
    const float2* __restrict__ P,
    float* __restrict__ out,          // [B,C,H,W] (+ loss at [TOKENS*4])
    float* __restrict__ acc,
    unsigned* __restrict__ cnt)
{
    int G = blockIdx.x * 256 + threadIdx.x;   // 0..65535
    int t = G >> 2;                           // token
    int q = G & 3;                            // slice-quarter

    float bv = 3.0e38f;
    int bi = 0;
#pragma unroll 8
    for (int i = 0; i < 32; ++i) {
        float2 p = P[(q * 32 + i) * TOKENS + t];
        if (p.x < bv) { bv = p.x; bi = __float_as_int(p.y); }  // ascending -> lowest idx
    }
    // combine the 4 quarters; tie -> lowest global index
#pragma unroll
    for (int m = 1; m <= 2; m <<= 1) {
        float ov = __shfl_xor(bv, m, 64);
        int   oi = __shfl_xor(bi, m, 64);
        if (ov < bv || (ov == bv && oi < bi)) { bv = ov; bi = oi; }
    }

    int b = t >> 12;
    int n = t & (HW - 1);
    const float* zb = z + b * (4 * HW) + n;
    float z0 = zb[0], z1 = zb[HW], z2 = zb[2 * HW], z3 = zb[3 * HW];
    float x0 = fmaf(w[3],  z3, fmaf(w[2],  z2, fmaf(w[1],  z1, fmaf(w[0],  z0, bias[0]))));
    float x1 = fmaf(w[7],  z3, fmaf(w[6],  z2, fmaf(w[5],  z1, fmaf(w[4],  z0, bias[1]))));
    float x2 = fmaf(w[11], z3, fmaf(w[10], z2, fmaf(w[9],  z1, fmaf(w[8],  z0, bias[2]))));
    float x3 = fmaf(w[15], z3, fmaf(w[14], z2, fmaf(w[13], z1, fmaf(w[12], z0, bias[3]))));

    float4 qv = CB[bi];
    float d0 = qv.x - x0, d1 = qv.y - x1, d2 = qv.z - x2, d3 = qv.w - x3;

    float ls = 0.0f;
    if (q == 0) {
        float* ob = out + b * (4 * HW) + n;
        ob[0]      = x0 + d0;    // straight-through: x + (q - x)
        ob[HW]     = x1 + d1;
        ob[2 * HW] = x2 + d2;
        ob[3 * HW] = x3 + d3;
        ls = d0 * d0 + d1 * d1 + d2 * d2 + d3 * d3;
    }

#pragma unroll
    for (int off = 32; off > 0; off >>= 1)
        ls += __shfl_down(ls, off, 64);
    __shared__ float wsum[4];
    if ((threadIdx.x & 63) == 0) wsum[threadIdx.x >> 6] = ls;
    __syncthreads();
    if (threadIdx.x == 0) {
        atomicAdd(acc, wsum[0] + wsum[1] + wsum[2] + wsum[3]);
        __threadfence();
        unsigned old = atomicAdd(cnt, 1u);
        if (old == gridDim.x - 1) {
            float m = atomicAdd(acc, 0.0f) * (1.0f / 65536.0f);  // mean over B*N*C
            out[TOKENS * 4] = m + 0.25f * m;   // codebook_loss + BETA*commitment
        }
    }
}

extern "C" void kernel_launch(void* const* d_in, const int* in_sizes, int n_in,
                              void* d_out, int out_size, void* d_ws, size_t ws_size,
                              hipStream_t stream)
{
    const float* z    = (const float*)d_in[0];
    const float* w    = (const float*)d_in[1];
    const float* bias = (const float*)d_in[2];
    const float* cb   = (const float*)d_in[3];
    float* out = (float*)d_out;

    char* ws = (char*)d_ws;
    float*    acc = (float*)ws;            // 4 B
    unsigned* cnt = (unsigned*)(ws + 256); // 4 B
    float2*   P   = (float2*)(ws + 1024);  // 16 MiB

    const float4* CB4 = (const float4*)cb;

    k_dist<<<NSLICE * NGROUP, 256, 0, stream>>>(z, w, bias, CB4, P, acc, cnt);
    k_out<<<TOKENS * 4 / 256, 256, 0, stream>>>(z, w, bias, CB4, P, out, acc, cnt);
}

// Round 5
// 39.551 us; speedup vs baseline: 1.3297x; 1.3297x over previous
//
#include <hip/hip_runtime.h>

// Problem constants (B=4, C=4, H=64, W=64, K=8192)
static constexpr int TOKENS = 16384;   // B*H*W
static constexpr int HW     = 4096;    // H*W
static constexpr int NSG    = 64;      // codebook slice-groups
static constexpr int ESG    = 128;     // entries per slice-group (NSG*ESG == 8192)
static constexpr int NGROUP = 16;      // token groups
static constexpr int GTOK   = 1024;    // tokens per group (NGROUP*GTOK == TOKENS)
static constexpr int TPT    = 4;       // tokens per thread in dist kernel

// ---------------------------------------------------------------------------
// Kernel 0: init the packed argmin array (must run every call — the harness
// does not re-poison between replays) + zero the loss accumulator/counter.
// ---------------------------------------------------------------------------
__global__ __launch_bounds__(256) void k_init(
    unsigned long long* __restrict__ A, float* __restrict__ acc,
    unsigned* __restrict__ cnt)
{
    int i = blockIdx.x * 256 + threadIdx.x;
    A[i] = 0xFFFFFFFFFFFFFFFFull;      // > any real key (real high word <= 0xFF80xxxx)
    if (i == 0) { *acc = 0.0f; *cnt = 0u; }
}

// ---------------------------------------------------------------------------
// Kernel 1: fused pre-quant conv + sliced distance argmin via atomicMin.
// 1024 blocks = 64 slice-groups x 16 token groups (4 blocks/CU).
// Codebook via wave-uniform scalar loads; inner loop pure VALU (8 inst/pair).
// key = sortable(D) << 32 | idx  ->  min key = min distance, ties -> low idx.
// ---------------------------------------------------------------------------
__global__ __launch_bounds__(256, 4) void k_dist(
    const float* __restrict__ z,      // [B,C,H,W]
    const float* __restrict__ w,      // [4,4]
    const float* __restrict__ bias,   // [4]
    const float4* __restrict__ CB,    // [8192]
    unsigned long long* __restrict__ A)
{
    const int bx  = blockIdx.x;
    const int g   = bx & (NGROUP - 1);
    const int s   = bx >> 4;          // NGROUP == 16
    const int tid = threadIdx.x;

    // Per-thread tokens: 1x1 conv recomputed from z (w/bias uniform -> s_loads).
    const int tbase = g * GTOK + tid;
    float m0[TPT], m1[TPT], m2[TPT], m3[TPT], bv[TPT], x2s[TPT];
    int bi[TPT];
#pragma unroll
    for (int j = 0; j < TPT; ++j) {
        int t = tbase + j * 256;
        int b = t >> 12;
        int n = t & (HW - 1);
        const float* zb = z + b * (4 * HW) + n;
        float z0 = zb[0], z1 = zb[HW], z2 = zb[2 * HW], z3 = zb[3 * HW];
        float x0 = fmaf(w[3],  z3, fmaf(w[2],  z2, fmaf(w[1],  z1, fmaf(w[0],  z0, bias[0]))));
        float x1 = fmaf(w[7],  z3, fmaf(w[6],  z2, fmaf(w[5],  z1, fmaf(w[4],  z0, bias[1]))));
        float x2 = fmaf(w[11], z3, fmaf(w[10], z2, fmaf(w[9],  z1, fmaf(w[8],  z0, bias[2]))));
        float x3 = fmaf(w[15], z3, fmaf(w[14], z2, fmaf(w[13], z1, fmaf(w[12], z0, bias[3]))));
        m0[j] = -2.0f * x0;
        m1[j] = -2.0f * x1;
        m2[j] = -2.0f * x2;
        m3[j] = -2.0f * x3;
        x2s[j] = fmaf(x3, x3, fmaf(x2, x2, fmaf(x1, x1, x0 * x0)));
        bv[j] = 3.0e38f;
        bi[j] = 0;
    }

    // Wave-uniform slice base -> scalar (SMEM) loads for the codebook.
    const int sbase = __builtin_amdgcn_readfirstlane(s * ESG);
    const float4* __restrict__ cs = CB + sbase;

    // score = |c|^2 - 2 x.c  (per-token |x|^2 added after the loop)
#pragma unroll 8
    for (int e = 0; e < ESG; ++e) {
        float4 c = cs[e];             // uniform address -> scalar pipe
        float cn = fmaf(c.w, c.w, fmaf(c.z, c.z, fmaf(c.y, c.y, c.x * c.x)));
#pragma unroll
        for (int j = 0; j < TPT; ++j) {
            float d = fmaf(m0[j], c.x, fmaf(m1[j], c.y, fmaf(m2[j], c.z, fmaf(m3[j], c.w, cn))));
            bool lt = d < bv[j];      // strict < keeps lowest idx in-range
            bv[j] = lt ? d : bv[j];
            bi[j] = lt ? e : bi[j];
        }
    }

    // Pack (distance, index) into a sortable 64-bit key; fire-and-forget atomic.
#pragma unroll
    for (int j = 0; j < TPT; ++j) {
        float D = bv[j] + x2s[j];     // full |x-c|^2 (may round slightly negative)
        unsigned u = __float_as_uint(D);
        u ^= (unsigned)((int)u >> 31) | 0x80000000u;   // monotone float->uint map
        unsigned long long key =
            ((unsigned long long)u << 32) | (unsigned)(sbase + bi[j]);
        atomicMin(&A[tbase + j * 256], key);
    }
}

// ---------------------------------------------------------------------------
// Kernel 2: unpack argmin + gather + straight-through output + loss.
// 64 blocks x 256 threads, 1 token/thread.
// ---------------------------------------------------------------------------
__global__ __launch_bounds__(256) void k_out(
    const float* __restrict__ z,
    const float* __restrict__ w,
    const float* __restrict__ bias,
    const float4* __restrict__ CB,
    const unsigned long long* __restrict__ A,
    float* __restrict__ out,          // [B,C,H,W] (+ loss at [TOKENS*4])
    float* __restrict__ acc,
    unsigned* __restrict__ cnt)
{
    int t = blockIdx.x * 256 + threadIdx.x;
    int b = t >> 12;
    int n = t & (HW - 1);

    const float* zb = z + b * (4 * HW) + n;
    float z0 = zb[0], z1 = zb[HW], z2 = zb[2 * HW], z3 = zb[3 * HW];
    float x0 = fmaf(w[3],  z3, fmaf(w[2],  z2, fmaf(w[1],  z1, fmaf(w[0],  z0, bias[0]))));
    float x1 = fmaf(w[7],  z3, fmaf(w[6],  z2, fmaf(w[5],  z1, fmaf(w[4],  z0, bias[1]))));
    float x2 = fmaf(w[11], z3, fmaf(w[10], z2, fmaf(w[9],  z1, fmaf(w[8],  z0, bias[2]))));
    float x3 = fmaf(w[15], z3, fmaf(w[14], z2, fmaf(w[13], z1, fmaf(w[12], z0, bias[3]))));

    int idx = (int)((unsigned)A[t] & 8191u);
    float4 qv = CB[idx];
    float d0 = qv.x - x0, d1 = qv.y - x1, d2 = qv.z - x2, d3 = qv.w - x3;

    float* ob = out + b * (4 * HW) + n;
    ob[0]      = x0 + d0;    // straight-through: x + (q - x)
    ob[HW]     = x1 + d1;
    ob[2 * HW] = x2 + d2;
    ob[3 * HW] = x3 + d3;

    float ls = fmaf(d3, d3, fmaf(d2, d2, fmaf(d1, d1, d0 * d0)));
#pragma unroll
    for (int off = 32; off > 0; off >>= 1)
        ls += __shfl_down(ls, off, 64);
    __shared__ float wsum[4];
    if ((threadIdx.x & 63) == 0) wsum[threadIdx.x >> 6] = ls;
    __syncthreads();
    if (threadIdx.x == 0) {
        atomicAdd(acc, wsum[0] + wsum[1] + wsum[2] + wsum[3]);
        __threadfence();
        unsigned old = atomicAdd(cnt, 1u);
        if (old == gridDim.x - 1) {
            float m = atomicAdd(acc, 0.0f) * (1.0f / 65536.0f);  // mean over B*N*C
            out[TOKENS * 4] = m + 0.25f * m;   // codebook_loss + BETA*commitment
        }
    }
}

extern "C" void kernel_launch(void* const* d_in, const int* in_sizes, int n_in,
                              void* d_out, int out_size, void* d_ws, size_t ws_size,
                              hipStream_t stream)
{
    const float* z    = (const float*)d_in[0];
    const float* w    = (const float*)d_in[1];
    const float* bias = (const float*)d_in[2];
    const float* cb   = (const float*)d_in[3];
    float* out = (float*)d_out;

    char* ws = (char*)d_ws;
    float*              acc = (float*)ws;                 // 4 B
    unsigned*           cnt = (unsigned*)(ws + 256);      // 4 B
    unsigned long long* A   = (unsigned long long*)(ws + 1024);  // 128 KiB

    const float4* CB4 = (const float4*)cb;

    k_init<<<TOKENS / 256, 256, 0, stream>>>(A, acc, cnt);
    k_dist<<<NSG * NGROUP, 256, 0, stream>>>(z, w, bias, CB4, A);
    k_out<<<TOKENS / 256, 256, 0, stream>>>(z, w, bias, CB4, A, out, acc, cnt);
}